// Round 12
// baseline (95.309 us; speedup 1.0000x reference)
//
#include <hip/hip_runtime.h>
#include <hip/hip_bf16.h>
#include <cstddef>

#define HW 2304
#define CD 256

typedef __bf16 bf16;
typedef bf16 bf16x8 __attribute__((ext_vector_type(8)));
typedef float f32x4 __attribute__((ext_vector_type(4)));

__device__ __forceinline__ unsigned short f2bf(float f) {
    unsigned u = __float_as_uint(f);
    u += 0x7fffu + ((u >> 16) & 1u);
    return (unsigned short)(u >> 16);
}

// ---- pass 1 (fused): convert mems + transpose k + coarse dots ----
// blocks [0,9216): convert; [9216,11520): transpose; [11520,11556): coarse
__global__ void prep(const float* __restrict__ g0, const float* __restrict__ g1,
                     const float* __restrict__ l0, const float* __restrict__ l1,
                     const float* __restrict__ k,
                     const float* __restrict__ c0, const float* __restrict__ c1,
                     const float* __restrict__ c2, const float* __restrict__ c3,
                     const float* __restrict__ c4, const float* __restrict__ c5,
                     unsigned short* __restrict__ outB,
                     unsigned short* __restrict__ kT,
                     float* __restrict__ out) {
    __shared__ float tile[32][33];
    const int bid = blockIdx.x;
    const int tid = threadIdx.x;
    if (bid < 9216) {
        // convert: layout [z][kt][n][32], physical chunk p = c ^ ((n>>1)&3)
        const int bx = bid % 576, z = bid / 576;
        const int b = z >> 2, t = z & 3;
        const float* src = t == 0 ? g0 : t == 1 ? g1 : t == 2 ? l0 : l1;
        const int kt = bx & 7;
        const int n0 = (bx >> 3) * 32;
        const int n = n0 + (tid >> 3);
        const int kk = (tid & 7) * 4;
        float4 v = *(const float4*)(src + (size_t)b * (HW * CD) + (size_t)n * CD + kt * 32 + kk);
        ushort4 o;
        o.x = f2bf(v.x); o.y = f2bf(v.y); o.z = f2bf(v.z); o.w = f2bf(v.w);
        const int p = (kk >> 3) ^ ((n >> 1) & 3);
        *(ushort4*)(outB + (size_t)z * (HW * CD) + (size_t)kt * (HW * 32)
                    + (size_t)n * 32 + p * 8 + (kk & 7)) = o;
    } else if (bid < 11520) {
        const int t3 = bid - 9216;              // orig grid (72,8,4)
        const int m0 = (t3 % 72) * 32;
        const int c0_ = ((t3 / 72) & 7) * 32;   // kt = c0_/32
        const int bz = t3 / 576;
        const int tx = tid & 31, ty = tid >> 5;
        const float* kb = k + (size_t)bz * CD * HW;
        #pragma unroll
        for (int s = 0; s < 32; s += 8)
            tile[ty + s][tx] = kb[(size_t)(c0_ + ty + s) * HW + m0 + tx];
        __syncthreads();
        unsigned short* kTb = kT + (size_t)bz * (HW * CD) + (size_t)(c0_ >> 5) * (HW * 32);
        #pragma unroll
        for (int s = 0; s < 32; s += 8) {
            const int m = m0 + ty + s;
            const int p = (tx >> 3) ^ ((m >> 1) & 3);
            kTb[(size_t)m * 32 + p * 8 + (tx & 7)] = f2bf(tile[tx][ty + s]);
        }
    } else {
        const int g = (bid - 11520) * 256 + tid;   // 36*256 = 9216 = 4*HW
        const int b = g / HW, m = g - b * HW;
        float a0 = 0, a1 = 0, a2 = 0, a3 = 0, a4 = 0, a5 = 0;
        const float* kb = k + (size_t)b * CD * HW;
        for (int c = 0; c < CD; ++c) {
            const float kv = kb[(size_t)c * HW + m];
            a0 = fmaf(c0[b * CD + c], kv, a0);
            a1 = fmaf(c1[b * CD + c], kv, a1);
            a2 = fmaf(c2[b * CD + c], kv, a2);
            a3 = fmaf(c3[b * CD + c], kv, a3);
            a4 = fmaf(c4[b * CD + c], kv, a4);
            a5 = fmaf(c5[b * CD + c], kv, a5);
        }
        out[((size_t)b * 10 + 4) * HW + m] = a0;
        out[((size_t)b * 10 + 5) * HW + m] = a1;
        out[((size_t)b * 10 + 6) * HW + m] = a2;
        out[((size_t)b * 10 + 7) * HW + m] = a3;
        out[((size_t)b * 10 + 8) * HW + m] = a4;
        out[((size_t)b * 10 + 9) * HW + m] = a5;
    }
}

// ---- pass 2: dual-t MFMA GEMM, 4-phase/K-step interleave, tri-buffer LDS,
// counted vmcnt (never drains mid-loop), setprio around MFMA clusters ----
// grid 2592. Balanced pair-swizzle: XCD pair {2c,2c+1} handles z-pair of batch c.
__global__ __launch_bounds__(256, 2)
void fine_gemm(const unsigned short* __restrict__ memsB,  // [z][kt][2304][32] swz
               const unsigned short* __restrict__ kT,     // [b][kt][2304][32] swz
               const float* __restrict__ sds,
               float* __restrict__ part) {
    __shared__ unsigned short A0l[3][128][32];   // 24KB
    __shared__ unsigned short A1l[3][128][32];   // 24KB
    __shared__ unsigned short Bl[3][128][32];    // 24KB

    const int h = blockIdx.x;
    const int x = h & 7, j = h >> 3;             // x = XCD slot, j in [0,324)
    const int c = x >> 1;                        // batch
    const int zp = c * 2 + (j & 1);              // pair index in {2c, 2c+1}
    const int idx = (x & 1) * 162 + (j >> 1);    // tile index in [0,324)
    const int mi = idx % 18, ni = idx / 18;
    const int b = zp >> 1, p = zp & 1, t0 = p * 2;
    const int z0 = b * 4 + t0;                   // first memory plane
    const int n0 = ni * 128, m0 = mi * 128;

    const int tid = threadIdx.x;
    const int lane = tid & 63;
    const int w = tid >> 6;
    const int wrow = w >> 1, wcol = w & 1;

    const unsigned short* A0g = memsB + (size_t)z0 * (HW * CD);
    const unsigned short* A1g = memsB + (size_t)(z0 + 1) * (HW * CD);
    const unsigned short* Bg  = kT + (size_t)b * (HW * CD);

    const int srow = lane >> 2;          // staging: row within 16-row stripe
    const int scol = (lane & 3) * 8;     // staging: physical 16B chunk
    const int lr = lane & 15;
    const int pofs = ((lane >> 4) ^ ((lr >> 1) & 3)) * 8;   // swizzled read chunk

    f32x4 acc0[4][4] = {};
    f32x4 acc1[4][4] = {};

// one global_load_lds of one 16-row stripe (s in {0,1}) of one array
#define STG1(buf, kt_, G, L, base, s)                                                      \
    do {                                                                                   \
        const size_t ko_ = (size_t)(kt_) * (HW * 32);                                      \
        const int r_ = w * 32 + (s) * 16;                                                  \
        const size_t go_ = ko_ + (size_t)((base) + r_ + srow) * 32 + scol;                 \
        __builtin_amdgcn_global_load_lds(                                                  \
            (const __attribute__((address_space(1))) unsigned int*)((G) + go_),            \
            (__attribute__((address_space(3))) unsigned int*)&L[buf][r_][0], 16, 0, 0);    \
    } while (0)

#define STG_ALL(buf, kt_)                                                                  \
    do {                                                                                   \
        STG1(buf, kt_, A0g, A0l, n0, 0); STG1(buf, kt_, A0g, A0l, n0, 1);                  \
        STG1(buf, kt_, A1g, A1l, n0, 0); STG1(buf, kt_, A1g, A1l, n0, 1);                  \
        STG1(buf, kt_, Bg,  Bl,  m0, 0); STG1(buf, kt_, Bg,  Bl,  m0, 1);                  \
    } while (0)

#define MFMA_ROW(i, a0v, a1v)                                                              \
    do {                                                                                   \
        __builtin_amdgcn_s_setprio(1);                                                     \
        _Pragma("unroll")                                                                  \
        for (int j2 = 0; j2 < 4; ++j2) {                                                   \
            acc0[i][j2] = __builtin_amdgcn_mfma_f32_16x16x32_bf16(a0v, bfr[j2], acc0[i][j2], 0, 0, 0); \
            acc1[i][j2] = __builtin_amdgcn_mfma_f32_16x16x32_bf16(a1v, bfr[j2], acc1[i][j2], 0, 0, 0); \
        }                                                                                  \
        __builtin_amdgcn_s_setprio(0);                                                     \
    } while (0)

#define WAIT_LGKM()                                                                        \
    do {                                                                                   \
        __builtin_amdgcn_s_barrier();                                                      \
        asm volatile("s_waitcnt lgkmcnt(0)" ::: "memory");                                 \
        __builtin_amdgcn_sched_barrier(0);                                                 \
    } while (0)

    // prologue: stage kt=0 -> buf0, kt=1 -> buf1 (12 loads in flight)
    STG_ALL(0, 0);
    STG_ALL(1, 1);

    #pragma unroll
    for (int kt = 0; kt < 8; ++kt) {
        const int cur = kt % 3;
        const int nb  = (kt + 2) % 3;
        // K-step top: stage(kt) landed; stage(kt+1)'s 6 loads stay in flight
        if (kt < 7) {
            asm volatile("s_waitcnt vmcnt(6)" ::: "memory");
        } else {
            asm volatile("s_waitcnt vmcnt(0)" ::: "memory");
        }
        __builtin_amdgcn_s_barrier();

        bf16x8 bfr[4];
        // ---- phase 0: B frags + row 0, stage 2 ----
        #pragma unroll
        for (int j2 = 0; j2 < 4; ++j2)
            bfr[j2] = *(const bf16x8*)&Bl[cur][wcol * 64 + j2 * 16 + lr][pofs];
        bf16x8 a0v = *(const bf16x8*)&A0l[cur][wrow * 64 + 0 * 16 + lr][pofs];
        bf16x8 a1v = *(const bf16x8*)&A1l[cur][wrow * 64 + 0 * 16 + lr][pofs];
        if (kt < 6) { STG1(nb, kt + 2, A0g, A0l, n0, 0); STG1(nb, kt + 2, A0g, A0l, n0, 1); }
        WAIT_LGKM();
        MFMA_ROW(0, a0v, a1v);
        __builtin_amdgcn_s_barrier();

        // ---- phase 1: row 1, stage 2 ----
        a0v = *(const bf16x8*)&A0l[cur][wrow * 64 + 1 * 16 + lr][pofs];
        a1v = *(const bf16x8*)&A1l[cur][wrow * 64 + 1 * 16 + lr][pofs];
        if (kt < 6) { STG1(nb, kt + 2, A1g, A1l, n0, 0); STG1(nb, kt + 2, A1g, A1l, n0, 1); }
        WAIT_LGKM();
        MFMA_ROW(1, a0v, a1v);
        __builtin_amdgcn_s_barrier();

        // ---- phase 2: row 2, stage 2 ----
        a0v = *(const bf16x8*)&A0l[cur][wrow * 64 + 2 * 16 + lr][pofs];
        a1v = *(const bf16x8*)&A1l[cur][wrow * 64 + 2 * 16 + lr][pofs];
        if (kt < 6) { STG1(nb, kt + 2, Bg, Bl, m0, 0); STG1(nb, kt + 2, Bg, Bl, m0, 1); }
        WAIT_LGKM();
        MFMA_ROW(2, a0v, a1v);
        __builtin_amdgcn_s_barrier();

        // ---- phase 3: row 3 (no stage; no end barrier — K-step top has one) ----
        a0v = *(const bf16x8*)&A0l[cur][wrow * 64 + 3 * 16 + lr][pofs];
        a1v = *(const bf16x8*)&A1l[cur][wrow * 64 + 3 * 16 + lr][pofs];
        WAIT_LGKM();
        MFMA_ROW(3, a0v, a1v);
    }
#undef STG1
#undef STG_ALL
#undef MFMA_ROW
#undef WAIT_LGKM

    // epilogue: sds scale for the local pair (p == 1), one read serves both t's
    if (p == 1) {
        const float* sb = sds + (size_t)b * HW * HW;
        #pragma unroll
        for (int i = 0; i < 4; ++i) {
            #pragma unroll
            for (int j2 = 0; j2 < 4; ++j2) {
                #pragma unroll
                for (int r = 0; r < 4; ++r) {
                    const int n = n0 + wrow * 64 + i * 16 + (lane >> 4) * 4 + r;
                    const int m = m0 + wcol * 64 + j2 * 16 + (lane & 15);
                    const float sv = sb[(size_t)n * HW + m];
                    acc0[i][j2][r] *= sv;
                    acc1[i][j2][r] *= sv;
                }
            }
        }
    }

    // column max over this wave's 64-row half, race-free per-wrow partial write
    #pragma unroll
    for (int j2 = 0; j2 < 4; ++j2) {
        float v0 = acc0[0][j2][0];
        float v1 = acc1[0][j2][0];
        #pragma unroll
        for (int i = 0; i < 4; ++i) {
            #pragma unroll
            for (int r = 0; r < 4; ++r) {
                v0 = fmaxf(v0, acc0[i][j2][r]);
                v1 = fmaxf(v1, acc1[i][j2][r]);
            }
        }
        v0 = fmaxf(v0, __shfl_xor(v0, 16));
        v0 = fmaxf(v0, __shfl_xor(v0, 32));
        v1 = fmaxf(v1, __shfl_xor(v1, 16));
        v1 = fmaxf(v1, __shfl_xor(v1, 32));
        if (lane < 16) {
            const int m = m0 + wcol * 64 + j2 * 16 + lane;
            part[((size_t)z0 * 36 + ni * 2 + wrow) * HW + m] = v0;
            part[((size_t)(z0 + 1) * 36 + ni * 2 + wrow) * HW + m] = v1;
        }
    }
}

// ---- pass 3: reduce partials over ni x wrow ----
__global__ void finalize(const float* __restrict__ part, float* __restrict__ out) {
    const int i = blockIdx.x * 256 + threadIdx.x;   // 144*256 = 36864 = 16*HW
    const int z = i / HW, m = i - z * HW;
    const int b = z >> 2, t = z & 3;
    float v = part[(size_t)z * 36 * HW + m];
    #pragma unroll
    for (int q = 1; q < 36; ++q)
        v = fmaxf(v, part[((size_t)z * 36 + q) * HW + m]);
    out[((size_t)b * 10 + t) * HW + m] = v;
}

extern "C" void kernel_launch(void* const* d_in, const int* in_sizes, int n_in,
                              void* d_out, int out_size, void* d_ws, size_t ws_size,
                              hipStream_t stream) {
    const float* norm_key = (const float*)d_in[0];
    const float* gbg = (const float*)d_in[1];
    const float* gfg = (const float*)d_in[2];
    const float* lbg = (const float*)d_in[3];
    const float* lfg = (const float*)d_in[4];
    const float* obg = (const float*)d_in[5];
    const float* ofg = (const float*)d_in[6];
    const float* sbg = (const float*)d_in[7];
    const float* sfg = (const float*)d_in[8];
    const float* lgbg = (const float*)d_in[9];
    const float* lgfg = (const float*)d_in[10];
    const float* sds = (const float*)d_in[11];
    float* out = (float*)d_out;

    // ws layout: [part f32 16*36*2304][memsB bf16 16*2304*256][kT bf16 4*2304*256]
    float* part = (float*)d_ws;
    const size_t part_bytes = (size_t)16 * 36 * HW * sizeof(float);          // ~5.3 MB
    unsigned short* memsB = (unsigned short*)((char*)d_ws + part_bytes);
    const size_t mems_bytes = (size_t)16 * HW * CD * sizeof(unsigned short); // ~18.9 MB
    unsigned short* kT = (unsigned short*)((char*)d_ws + part_bytes + mems_bytes);

    prep<<<11556, 256, 0, stream>>>(gbg, gfg, lbg, lfg, norm_key,
                                    obg, ofg, sbg, sfg, lgbg, lgfg,
                                    memsB, kT, out);
    fine_gemm<<<2592, 256, 0, stream>>>(memsB, kT, sds, part);
    finalize<<<144, 256, 0, stream>>>(part, out);
}

// Round 13
// 93.308 us; speedup vs baseline: 1.0214x; 1.0214x over previous
//
#include <hip/hip_runtime.h>
#include <hip/hip_bf16.h>
#include <cstddef>

#define HW 2304
#define CD 256

typedef __bf16 bf16;
typedef bf16 bf16x8 __attribute__((ext_vector_type(8)));
typedef float f32x4 __attribute__((ext_vector_type(4)));

__device__ __forceinline__ unsigned short f2bf(float f) {
    unsigned u = __float_as_uint(f);
    u += 0x7fffu + ((u >> 16) & 1u);
    return (unsigned short)(u >> 16);
}

// ---- pass 1 (fused): convert mems + transpose k + coarse dots ----
// blocks [0,9216): convert; [9216,11520): transpose; [11520,11556): coarse
__global__ void prep(const float* __restrict__ g0, const float* __restrict__ g1,
                     const float* __restrict__ l0, const float* __restrict__ l1,
                     const float* __restrict__ k,
                     const float* __restrict__ c0, const float* __restrict__ c1,
                     const float* __restrict__ c2, const float* __restrict__ c3,
                     const float* __restrict__ c4, const float* __restrict__ c5,
                     unsigned short* __restrict__ outB,
                     unsigned short* __restrict__ kT,
                     float* __restrict__ out) {
    __shared__ float tile[32][33];
    const int bid = blockIdx.x;
    const int tid = threadIdx.x;
    if (bid < 9216) {
        // convert: layout [z][kt][n][32], physical chunk p = c ^ ((n>>1)&3)
        const int bx = bid % 576, z = bid / 576;
        const int b = z >> 2, t = z & 3;
        const float* src = t == 0 ? g0 : t == 1 ? g1 : t == 2 ? l0 : l1;
        const int kt = bx & 7;
        const int n0 = (bx >> 3) * 32;
        const int n = n0 + (tid >> 3);
        const int kk = (tid & 7) * 4;
        float4 v = *(const float4*)(src + (size_t)b * (HW * CD) + (size_t)n * CD + kt * 32 + kk);
        ushort4 o;
        o.x = f2bf(v.x); o.y = f2bf(v.y); o.z = f2bf(v.z); o.w = f2bf(v.w);
        const int p = (kk >> 3) ^ ((n >> 1) & 3);
        *(ushort4*)(outB + (size_t)z * (HW * CD) + (size_t)kt * (HW * 32)
                    + (size_t)n * 32 + p * 8 + (kk & 7)) = o;
    } else if (bid < 11520) {
        const int t3 = bid - 9216;              // orig grid (72,8,4)
        const int m0 = (t3 % 72) * 32;
        const int c0_ = ((t3 / 72) & 7) * 32;   // kt = c0_/32
        const int bz = t3 / 576;
        const int tx = tid & 31, ty = tid >> 5;
        const float* kb = k + (size_t)bz * CD * HW;
        #pragma unroll
        for (int s = 0; s < 32; s += 8)
            tile[ty + s][tx] = kb[(size_t)(c0_ + ty + s) * HW + m0 + tx];
        __syncthreads();
        unsigned short* kTb = kT + (size_t)bz * (HW * CD) + (size_t)(c0_ >> 5) * (HW * 32);
        #pragma unroll
        for (int s = 0; s < 32; s += 8) {
            const int m = m0 + ty + s;
            const int p = (tx >> 3) ^ ((m >> 1) & 3);
            kTb[(size_t)m * 32 + p * 8 + (tx & 7)] = f2bf(tile[tx][ty + s]);
        }
    } else {
        const int g = (bid - 11520) * 256 + tid;   // 36*256 = 9216 = 4*HW
        const int b = g / HW, m = g - b * HW;
        float a0 = 0, a1 = 0, a2 = 0, a3 = 0, a4 = 0, a5 = 0;
        const float* kb = k + (size_t)b * CD * HW;
        for (int c = 0; c < CD; ++c) {
            const float kv = kb[(size_t)c * HW + m];
            a0 = fmaf(c0[b * CD + c], kv, a0);
            a1 = fmaf(c1[b * CD + c], kv, a1);
            a2 = fmaf(c2[b * CD + c], kv, a2);
            a3 = fmaf(c3[b * CD + c], kv, a3);
            a4 = fmaf(c4[b * CD + c], kv, a4);
            a5 = fmaf(c5[b * CD + c], kv, a5);
        }
        out[((size_t)b * 10 + 4) * HW + m] = a0;
        out[((size_t)b * 10 + 5) * HW + m] = a1;
        out[((size_t)b * 10 + 6) * HW + m] = a2;
        out[((size_t)b * 10 + 7) * HW + m] = a3;
        out[((size_t)b * 10 + 8) * HW + m] = a4;
        out[((size_t)b * 10 + 9) * HW + m] = a5;
    }
}

// ---- pass 2: dual-t MFMA GEMM, TRI-BUFFER LDS, counted vmcnt (no drain),
// ONE barrier per K-step, compiler-interleaved ds_read/MFMA ----
// Safety: a wave reaching kt's barrier has consumed (lgkm-retired) all its
// kt-1 ds_reads of buf[(kt+2)%3], so re-staging it after the barrier is safe.
// grid 2592. Balanced pair-swizzle: XCD pair {2c,2c+1} handles z-pair of batch c.
__global__ __launch_bounds__(256, 2)
void fine_gemm(const unsigned short* __restrict__ memsB,  // [z][kt][2304][32] swz
               const unsigned short* __restrict__ kT,     // [b][kt][2304][32] swz
               const float* __restrict__ sds,
               float* __restrict__ part) {
    __shared__ unsigned short A0l[3][128][32];   // 24KB
    __shared__ unsigned short A1l[3][128][32];   // 24KB
    __shared__ unsigned short Bl[3][128][32];    // 24KB

    const int h = blockIdx.x;
    const int x = h & 7, j = h >> 3;             // x = XCD slot, j in [0,324)
    const int c = x >> 1;                        // batch
    const int zp = c * 2 + (j & 1);              // pair index in {2c, 2c+1}
    const int idx = (x & 1) * 162 + (j >> 1);    // tile index in [0,324)
    const int mi = idx % 18, ni = idx / 18;
    const int b = zp >> 1, p = zp & 1, t0 = p * 2;
    const int z0 = b * 4 + t0;                   // first memory plane
    const int n0 = ni * 128, m0 = mi * 128;

    const int tid = threadIdx.x;
    const int lane = tid & 63;
    const int w = tid >> 6;
    const int wrow = w >> 1, wcol = w & 1;

    const unsigned short* A0g = memsB + (size_t)z0 * (HW * CD);
    const unsigned short* A1g = memsB + (size_t)(z0 + 1) * (HW * CD);
    const unsigned short* Bg  = kT + (size_t)b * (HW * CD);

    const int srow = lane >> 2;          // staging: row within 16-row stripe
    const int scol = (lane & 3) * 8;     // staging: physical 16B chunk
    const int lr = lane & 15;
    const int pofs = ((lane >> 4) ^ ((lr >> 1) & 3)) * 8;   // swizzled read chunk

    f32x4 acc0[4][4] = {};
    f32x4 acc1[4][4] = {};

#define STAGE(buf, kt_)                                                                    \
    do {                                                                                   \
        const size_t ko = (size_t)(kt_) * (HW * 32);                                       \
        _Pragma("unroll")                                                                  \
        for (int s = 0; s < 2; ++s) {                                                      \
            const int r = w * 32 + s * 16;                                                 \
            const size_t goa = ko + (size_t)(n0 + r + srow) * 32 + scol;                   \
            const size_t gob = ko + (size_t)(m0 + r + srow) * 32 + scol;                   \
            __builtin_amdgcn_global_load_lds(                                              \
                (const __attribute__((address_space(1))) unsigned int*)(A0g + goa),        \
                (__attribute__((address_space(3))) unsigned int*)&A0l[buf][r][0], 16, 0, 0); \
            __builtin_amdgcn_global_load_lds(                                              \
                (const __attribute__((address_space(1))) unsigned int*)(A1g + goa),        \
                (__attribute__((address_space(3))) unsigned int*)&A1l[buf][r][0], 16, 0, 0); \
            __builtin_amdgcn_global_load_lds(                                              \
                (const __attribute__((address_space(1))) unsigned int*)(Bg + gob),         \
                (__attribute__((address_space(3))) unsigned int*)&Bl[buf][r][0], 16, 0, 0); \
        }                                                                                  \
    } while (0)

    // prologue: stage kt=0 -> buf0, kt=1 -> buf1 (12 loads in flight)
    STAGE(0, 0);
    STAGE(1, 1);

    #pragma unroll
    for (int kt = 0; kt < 8; ++kt) {
        const int cur = kt % 3;
        const int nb  = (kt + 2) % 3;

        // counted wait: stage(kt) landed; stage(kt+1)'s 6 loads stay in flight
        if (kt < 7) {
            asm volatile("s_waitcnt vmcnt(6)" ::: "memory");
        } else {
            asm volatile("s_waitcnt vmcnt(0)" ::: "memory");
        }
        __builtin_amdgcn_s_barrier();   // sole barrier: buf[nb]'s kt-1 readers done

        // re-stage buf[nb] with tile kt+2 (lands during this + next K-step)
        if (kt < 6) STAGE(nb, kt + 2);

        // plain fragment reads: compiler interleaves counted lgkm with MFMAs
        bf16x8 a0f[4], a1f[4], bfr[4];
        #pragma unroll
        for (int i = 0; i < 4; ++i) {
            a0f[i] = *(const bf16x8*)&A0l[cur][wrow * 64 + i * 16 + lr][pofs];
            a1f[i] = *(const bf16x8*)&A1l[cur][wrow * 64 + i * 16 + lr][pofs];
            bfr[i] = *(const bf16x8*)&Bl[cur][wcol * 64 + i * 16 + lr][pofs];
        }

        __builtin_amdgcn_s_setprio(1);
        #pragma unroll
        for (int i = 0; i < 4; ++i) {
            #pragma unroll
            for (int j2 = 0; j2 < 4; ++j2) {
                acc0[i][j2] = __builtin_amdgcn_mfma_f32_16x16x32_bf16(a0f[i], bfr[j2], acc0[i][j2], 0, 0, 0);
                acc1[i][j2] = __builtin_amdgcn_mfma_f32_16x16x32_bf16(a1f[i], bfr[j2], acc1[i][j2], 0, 0, 0);
            }
        }
        __builtin_amdgcn_s_setprio(0);
        // no end barrier: next iteration's top barrier is the sync point
    }
#undef STAGE

    // epilogue: sds scale for the local pair (p == 1), one read serves both t's
    if (p == 1) {
        const float* sb = sds + (size_t)b * HW * HW;
        #pragma unroll
        for (int i = 0; i < 4; ++i) {
            #pragma unroll
            for (int j2 = 0; j2 < 4; ++j2) {
                #pragma unroll
                for (int r = 0; r < 4; ++r) {
                    const int n = n0 + wrow * 64 + i * 16 + (lane >> 4) * 4 + r;
                    const int m = m0 + wcol * 64 + j2 * 16 + (lane & 15);
                    const float sv = sb[(size_t)n * HW + m];
                    acc0[i][j2][r] *= sv;
                    acc1[i][j2][r] *= sv;
                }
            }
        }
    }

    // column max over this wave's 64-row half, race-free per-wrow partial write
    #pragma unroll
    for (int j2 = 0; j2 < 4; ++j2) {
        float v0 = acc0[0][j2][0];
        float v1 = acc1[0][j2][0];
        #pragma unroll
        for (int i = 0; i < 4; ++i) {
            #pragma unroll
            for (int r = 0; r < 4; ++r) {
                v0 = fmaxf(v0, acc0[i][j2][r]);
                v1 = fmaxf(v1, acc1[i][j2][r]);
            }
        }
        v0 = fmaxf(v0, __shfl_xor(v0, 16));
        v0 = fmaxf(v0, __shfl_xor(v0, 32));
        v1 = fmaxf(v1, __shfl_xor(v1, 16));
        v1 = fmaxf(v1, __shfl_xor(v1, 32));
        if (lane < 16) {
            const int m = m0 + wcol * 64 + j2 * 16 + lane;
            part[((size_t)z0 * 36 + ni * 2 + wrow) * HW + m] = v0;
            part[((size_t)(z0 + 1) * 36 + ni * 2 + wrow) * HW + m] = v1;
        }
    }
}

// ---- pass 3: reduce partials over ni x wrow ----
__global__ void finalize(const float* __restrict__ part, float* __restrict__ out) {
    const int i = blockIdx.x * 256 + threadIdx.x;   // 144*256 = 36864 = 16*HW
    const int z = i / HW, m = i - z * HW;
    const int b = z >> 2, t = z & 3;
    float v = part[(size_t)z * 36 * HW + m];
    #pragma unroll
    for (int q = 1; q < 36; ++q)
        v = fmaxf(v, part[((size_t)z * 36 + q) * HW + m]);
    out[((size_t)b * 10 + t) * HW + m] = v;
}

extern "C" void kernel_launch(void* const* d_in, const int* in_sizes, int n_in,
                              void* d_out, int out_size, void* d_ws, size_t ws_size,
                              hipStream_t stream) {
    const float* norm_key = (const float*)d_in[0];
    const float* gbg = (const float*)d_in[1];
    const float* gfg = (const float*)d_in[2];
    const float* lbg = (const float*)d_in[3];
    const float* lfg = (const float*)d_in[4];
    const float* obg = (const float*)d_in[5];
    const float* ofg = (const float*)d_in[6];
    const float* sbg = (const float*)d_in[7];
    const float* sfg = (const float*)d_in[8];
    const float* lgbg = (const float*)d_in[9];
    const float* lgfg = (const float*)d_in[10];
    const float* sds = (const float*)d_in[11];
    float* out = (float*)d_out;

    // ws layout: [part f32 16*36*2304][memsB bf16 16*2304*256][kT bf16 4*2304*256]
    float* part = (float*)d_ws;
    const size_t part_bytes = (size_t)16 * 36 * HW * sizeof(float);          // ~5.3 MB
    unsigned short* memsB = (unsigned short*)((char*)d_ws + part_bytes);
    const size_t mems_bytes = (size_t)16 * HW * CD * sizeof(unsigned short); // ~18.9 MB
    unsigned short* kT = (unsigned short*)((char*)d_ws + part_bytes + mems_bytes);

    prep<<<11556, 256, 0, stream>>>(gbg, gfg, lbg, lfg, norm_key,
                                    obg, ofg, sbg, sfg, lgbg, lgfg,
                                    memsB, kT, out);
    fine_gemm<<<2592, 256, 0, stream>>>(memsB, kT, sds, part);
    finalize<<<144, 256, 0, stream>>>(part, out);
}